// Round 2
// baseline (998.438 us; speedup 1.0000x reference)
//
#include <hip/hip_runtime.h>
#include <hip/hip_bf16.h>
#include <cstdint>
#include <cstddef>

// ---------- types ----------
typedef __attribute__((ext_vector_type(8))) short    bf16x8;   // 8 bf16 = 4 VGPRs (MFMA A/B frag)
typedef __attribute__((ext_vector_type(4))) float    f32x4;    // MFMA C/D frag
typedef __attribute__((ext_vector_type(8))) unsigned short u16x8;
typedef __attribute__((ext_vector_type(4))) float    f32v4;
typedef __attribute__((ext_vector_type(4))) unsigned short u16v4;

__device__ __forceinline__ float b2f(unsigned short v) {
    return __builtin_bit_cast(float, ((unsigned int)v) << 16);
}
__device__ __forceinline__ unsigned short f2b(float f) {
    unsigned int u = __builtin_bit_cast(unsigned int, f);
    u += 0x7fffu + ((u >> 16) & 1u);        // RNE
    return (unsigned short)(u >> 16);
}

__device__ __forceinline__ void async16(const void* g, void* l) {
    __builtin_amdgcn_global_load_lds(
        (const __attribute__((address_space(1))) unsigned int*)g,
        (__attribute__((address_space(3))) unsigned int*)l, 16, 0, 0);
}

// ---------- f32 -> bf16 convert ----------
__global__ __launch_bounds__(256) void cvt_f32_bf16(const float* __restrict__ src,
                                                    unsigned short* __restrict__ dst, int n4) {
    int i = blockIdx.x * blockDim.x + threadIdx.x;
    int stride = gridDim.x * blockDim.x;
    const f32v4* s4 = (const f32v4*)src;
    u16v4* d4 = (u16v4*)dst;
    for (; i < n4; i += stride) {
        f32v4 v = s4[i];
        u16v4 o;
        o.x = f2b(v.x); o.y = f2b(v.y); o.z = f2b(v.z); o.w = f2b(v.w);
        d4[i] = o;
    }
}

// ---------- bf16 MFMA GEMM: C[m][n] = sum_k A[m][k]*Bw[n][k] + bias[n] ----------
// MODE 0: Cout = float, row-major [M][N]
// MODE 1: Cout = bf16, "u layout": Cout[(b*CH + n)*Lseq + l], m = b*Lseq + l (tile never straddles b)
template <int MODE>
__global__ __launch_bounds__(256, 2) void gemm_bf16(
    const unsigned short* __restrict__ A,   // M x K bf16 row-major
    const unsigned short* __restrict__ Bw,  // N x K bf16 row-major
    const float* __restrict__ bias,         // N
    void* __restrict__ Cout,
    int M, int N, int K, int Lseq, int CH)
{
    constexpr int SMEM_N = (MODE == 1) ? 16384 : 8192;
    __shared__ unsigned short smem[SMEM_N];  // A tile [128][32] @0, B tile [128][32] @4096 (ushort idx)

    const int tid  = threadIdx.x;
    const int w    = tid >> 6;
    const int lane = tid & 63;
    const int quad = lane >> 4;
    const int lq   = lane & 15;
    const int n0 = blockIdx.x * 128;
    const int m0 = blockIdx.y * 128;
    const int wave_m = w & 1, wave_n = w >> 1;

    // staging: each wave copies 2KB of A + 2KB of B per K-step, 16B/lane/inst
    const int rSub = w * 32 + (lane >> 2);
    const int kcol = (lane & 3) * 8;
    const unsigned short* pA0 = A  + (size_t)(m0 + rSub)      * K + kcol;
    const unsigned short* pA1 = A  + (size_t)(m0 + rSub + 16) * K + kcol;
    const unsigned short* pB0 = Bw + (size_t)(n0 + rSub)      * K + kcol;
    const unsigned short* pB1 = Bw + (size_t)(n0 + rSub + 16) * K + kcol;
    char* sb = (char*)smem;
    char* dA0 = sb + w * 2048;
    char* dA1 = sb + w * 2048 + 1024;
    char* dB0 = sb + 8192 + w * 2048;
    char* dB1 = sb + 8192 + w * 2048 + 1024;

    f32x4 acc[4][4] = {};

    const int nIter = K >> 5;
    for (int kt = 0; kt < nIter; ++kt) {
        async16(pA0, dA0); async16(pA1, dA1);
        async16(pB0, dB0); async16(pB1, dB1);
        pA0 += 32; pA1 += 32; pB0 += 32; pB1 += 32;
        __syncthreads();   // drains vmcnt before LDS reads
        bf16x8 af[4], bw[4];
        #pragma unroll
        for (int i = 0; i < 4; ++i) {
            af[i] = *(const bf16x8*)&smem[(wave_m * 64 + i * 16 + lq) * 32 + quad * 8];
            bw[i] = *(const bf16x8*)&smem[4096 + (wave_n * 64 + i * 16 + lq) * 32 + quad * 8];
        }
        #pragma unroll
        for (int i = 0; i < 4; ++i)
            #pragma unroll
            for (int j = 0; j < 4; ++j)
                acc[i][j] = __builtin_amdgcn_mfma_f32_16x16x32_bf16(af[i], bw[j], acc[i][j], 0, 0, 0);
        __syncthreads();   // protect smem before next staging
    }

    if (MODE == 0) {
        float* out = (float*)Cout;
        #pragma unroll
        for (int j = 0; j < 4; ++j) {
            const int col = n0 + wave_n * 64 + j * 16 + lq;
            const float bv = bias[col];
            #pragma unroll
            for (int i = 0; i < 4; ++i) {
                const int rowb = m0 + wave_m * 64 + i * 16 + quad * 4;
                f32x4 c = acc[i][j];
                out[(size_t)(rowb + 0) * N + col] = c.x + bv;
                out[(size_t)(rowb + 1) * N + col] = c.y + bv;
                out[(size_t)(rowb + 2) * N + col] = c.z + bv;
                out[(size_t)(rowb + 3) * N + col] = c.w + bv;
            }
        }
    } else {
        // transpose through LDS so output rows (fixed channel, contiguous l) store coalesced
        #pragma unroll
        for (int j = 0; j < 4; ++j) {
            const int nl = wave_n * 64 + j * 16 + lq;
            const float bv = bias[n0 + nl];
            #pragma unroll
            for (int i = 0; i < 4; ++i) {
                const int ml = wave_m * 64 + i * 16 + quad * 4;
                f32x4 c = acc[i][j];
                smem[nl * 128 + ml + 0] = f2b(c.x + bv);
                smem[nl * 128 + ml + 1] = f2b(c.y + bv);
                smem[nl * 128 + ml + 2] = f2b(c.z + bv);
                smem[nl * 128 + ml + 3] = f2b(c.w + bv);
            }
        }
        __syncthreads();
        unsigned short* uo = (unsigned short*)Cout;
        const int bI = m0 >> 12;        // 4096 rows per batch
        const int l0 = m0 & 4095;
        // full 128x128 tile: 2048 chunks of 8 ushorts (16B/lane, coalesced)
        for (int e = tid; e < 2048; e += 256) {
            const int nl = e >> 4, seg = e & 15;
            u16x8 v = *(const u16x8*)&smem[nl * 128 + seg * 8];
            *(u16x8*)&uo[(size_t)(bI * CH + n0 + nl) * Lseq + l0 + seg * 8] = v;
        }
    }
}

// ---------- Hyena filter k(D,L) ----------
__global__ __launch_bounds__(256) void filter_kernel(
    const float* __restrict__ w0, const float* __restrict__ b0,
    const float* __restrict__ freq,
    const float* __restrict__ w1, const float* __restrict__ b1,
    const float* __restrict__ w2, const float* __restrict__ b2,
    const float* __restrict__ w3, float* __restrict__ kf)
{
    __shared__ float ha[64][64];
    __shared__ float hb[64][64];
    const int tid = threadIdx.x;
    const int l0 = blockIdx.x * 64;
    const int d0 = blockIdx.y * 256;
    const int l  = tid & 63;
    const int lg = l0 + l;
    const float tt = (float)lg * (1.0f / 4095.0f);
    const float wang = 6.283185307179586f * (float)lg * (1.0f / 4096.0f);
    const float a  = 1e-4f * wang;
    const float z0 = tt, z1 = cosf(a), z2 = -sinf(a);

    for (int e = tid; e < 4096; e += 256) {
        const int dim = e >> 6;
        float pre = z0 * w0[dim * 3] + z1 * w0[dim * 3 + 1] + z2 * w0[dim * 3 + 2] + b0[dim];
        ha[dim][l] = sinf(freq[dim] * pre);
    }
    __syncthreads();
    for (int e = tid; e < 4096; e += 256) {
        const int dim = e >> 6;
        float acc = b1[dim];
        #pragma unroll
        for (int jj = 0; jj < 64; ++jj) acc += w1[dim * 64 + jj] * ha[jj][l];
        hb[dim][l] = sinf(freq[dim] * acc);
    }
    __syncthreads();
    for (int e = tid; e < 4096; e += 256) {
        const int dim = e >> 6;
        float acc = b2[dim];
        #pragma unroll
        for (int jj = 0; jj < 64; ++jj) acc += w2[dim * 64 + jj] * hb[jj][l];
        ha[dim][l] = sinf(freq[dim] * acc);
    }
    __syncthreads();
    for (int d = d0 + (tid >> 6); d < d0 + 256; d += 4) {
        float acc = 0.f;
        #pragma unroll
        for (int jj = 0; jj < 64; ++jj) acc += w3[d * 64 + jj] * ha[jj][l];
        // deltas = linspace(ln(.01)/1.5, ln(.01)/0.3, 2048); decay = exp(-t*|delta|)
        const float delta = fabsf(-3.0701134573253944f + (-5.999245642062483e-3f) * (float)d);
        kf[(size_t)d * 4096 + lg] = acc * __expf(-tt * delta);
    }
}

// ---------- FFT helpers (8192-pt, 512 threads, data in LDS) ----------
__device__ __forceinline__ void fft8192_dif(float* re, float* im, int t) {
    // forward DFT, natural in -> bit-reversed out, twiddle exp(-2*pi*i*j/m)
    for (int m = 8192; m >= 2; m >>= 1) {
        const int hm = m >> 1;
        const float wconst = -6.283185307179586f / (float)m;
        #pragma unroll
        for (int s = 0; s < 8; ++s) {
            const int p  = t + (s << 9);
            const int j  = p & (hm - 1);
            const int i1 = ((p & ~(hm - 1)) << 1) | j;
            const int i2 = i1 + hm;
            const float ur = re[i1], ui = im[i1];
            const float vr = re[i2], vi = im[i2];
            float sn, cs; __sincosf(wconst * (float)j, &sn, &cs);
            re[i1] = ur + vr; im[i1] = ui + vi;
            const float dr = ur - vr, di = ui - vi;
            re[i2] = dr * cs - di * sn;
            im[i2] = dr * sn + di * cs;
        }
        __syncthreads();
    }
}

// ---------- fused: short conv + gate + fftconv + bias + x0 gate -> zb (B,D,L) bf16 ----------
__global__ __launch_bounds__(512, 1) void hyena_fft_kernel(
    const unsigned short* __restrict__ u,   // (B, 3D, L) bf16
    const float* __restrict__ kf,           // (D, L)
    const float* __restrict__ sw,           // (3D, 1, 3)
    const float* __restrict__ sbv,          // (3D)
    const float* __restrict__ fbias,        // (D)
    unsigned short* __restrict__ zb)        // (B, D, L) bf16
{
    __shared__ float fre[8192];
    __shared__ float fim[8192];
    const int t = threadIdx.x;
    const int d = blockIdx.x;

    // ---- K = FFT(k_d zero-padded) ----
    for (int s = 0; s < 16; ++s) {
        const int idx = t + (s << 9);
        fre[idx] = (idx < 4096) ? kf[(size_t)d * 4096 + idx] : 0.f;
        fim[idx] = 0.f;
    }
    __syncthreads();
    fft8192_dif(fre, fim, t);

    float kr[16], ki[16];
    #pragma unroll
    for (int s = 0; s < 16; ++s) { const int idx = t + (s << 9); kr[s] = fre[idx]; ki[s] = fim[idx]; }
    // (each thread overwrites only its own idx set below -> no barrier needed)

    // ---- short conv (causal, taps w0*u[l-2]+w1*u[l-1]+w2*u[l]) + gating ----
    const int c0 = d, c1 = 2048 + d, c2 = 4096 + d;
    const float w00 = sw[c0*3+0], w01 = sw[c0*3+1], w02 = sw[c0*3+2], bb0 = sbv[c0];
    const float w10 = sw[c1*3+0], w11 = sw[c1*3+1], w12 = sw[c1*3+2], bb1 = sbv[c1];
    const float w20 = sw[c2*3+0], w21 = sw[c2*3+1], w22 = sw[c2*3+2], bb2 = sbv[c2];
    const float fb = fbias[d];

    float vgr_[2][8], x0r_[2][8];
    #pragma unroll
    for (int s = 0; s < 8; ++s) {
        const int l = t + (s << 9);
        #pragma unroll
        for (int b = 0; b < 2; ++b) {
            const size_t base = (size_t)b * 6144 * 4096;
            const size_t r0 = base + (size_t)c0 * 4096;
            const size_t r1 = base + (size_t)c1 * 4096;
            const size_t r2 = base + (size_t)c2 * 4096;
            const float a0 = b2f(u[r0 + l]);
            const float a1 = (l >= 1) ? b2f(u[r0 + l - 1]) : 0.f;
            const float a2 = (l >= 2) ? b2f(u[r0 + l - 2]) : 0.f;
            const float x0v = w00 * a2 + w01 * a1 + w02 * a0 + bb0;
            const float e0 = b2f(u[r1 + l]);
            const float e1 = (l >= 1) ? b2f(u[r1 + l - 1]) : 0.f;
            const float e2 = (l >= 2) ? b2f(u[r1 + l - 2]) : 0.f;
            const float x1v = w10 * e2 + w11 * e1 + w12 * e0 + bb1;
            const float g0 = b2f(u[r2 + l]);
            const float g1 = (l >= 1) ? b2f(u[r2 + l - 1]) : 0.f;
            const float g2 = (l >= 2) ? b2f(u[r2 + l - 2]) : 0.f;
            const float vv = w20 * g2 + w21 * g1 + w22 * g0 + bb2;
            const float vg = vv * x1v;
            vgr_[b][s] = vg; x0r_[b][s] = x0v;
            if (b == 0) fre[l] = vg; else fim[l] = vg;
        }
    }
    #pragma unroll
    for (int s = 8; s < 16; ++s) { const int idx = t + (s << 9); fre[idx] = 0.f; fim[idx] = 0.f; }
    __syncthreads();

    // ---- C = FFT(vg0 + i*vg1); linearity: IFFT(C*K) = conv(vg0,k) + i*conv(vg1,k) ----
    fft8192_dif(fre, fim, t);

    #pragma unroll
    for (int s = 0; s < 16; ++s) {
        const int idx = t + (s << 9);
        const float cr = fre[idx], ci = fim[idx];
        fre[idx] = cr * kr[s] - ci * ki[s];
        fim[idx] = cr * ki[s] + ci * kr[s];
    }
    __syncthreads();

    // ---- inverse DIT (bit-reversed in -> natural out), twiddle exp(+2*pi*i*j/m) ----
    for (int m = 2; m <= 4096; m <<= 1) {
        const int hm = m >> 1;
        const float wconst = 6.283185307179586f / (float)m;
        #pragma unroll
        for (int s = 0; s < 8; ++s) {
            const int p  = t + (s << 9);
            const int j  = p & (hm - 1);
            const int i1 = ((p & ~(hm - 1)) << 1) | j;
            const int i2 = i1 + hm;
            float sn, cs; __sincosf(wconst * (float)j, &sn, &cs);
            const float vr = fre[i2] * cs - fim[i2] * sn;
            const float vi = fre[i2] * sn + fim[i2] * cs;
            const float ur = fre[i1], ui = fim[i1];
            fre[i1] = ur + vr; fim[i1] = ui + vi;
            fre[i2] = ur - vr; fim[i2] = ui - vi;
        }
        __syncthreads();
    }
    // final stage (m=8192) fused with epilogue; keep only outputs l<4096
    const float inv_n = 1.0f / 8192.0f;
    #pragma unroll
    for (int s = 0; s < 8; ++s) {
        const int p = t + (s << 9);
        float sn, cs; __sincosf(6.283185307179586f * (float)p * (1.0f / 8192.0f), &sn, &cs);
        const float vr = fre[p + 4096] * cs - fim[p + 4096] * sn;
        const float vi = fre[p + 4096] * sn + fim[p + 4096] * cs;
        const float yr = (fre[p] + vr) * inv_n;
        const float yi = (fim[p] + vi) * inv_n;
        const float z0 = (yr + vgr_[0][s] * fb) * x0r_[0][s];
        const float z1 = (yi + vgr_[1][s] * fb) * x0r_[1][s];
        zb[(size_t)d * 4096 + p]          = f2b(z0);
        zb[(size_t)(2048 + d) * 4096 + p] = f2b(z1);
    }
}

// ---------- (B,D,L) bf16 -> (B,L,D) bf16 transpose ----------
__global__ __launch_bounds__(256) void transpose_kernel(const unsigned short* __restrict__ zb,
                                                        unsigned short* __restrict__ zt)
{
    __shared__ unsigned int tile[64][65];
    const int l0 = blockIdx.x * 64, d0 = blockIdx.y * 64, b = blockIdx.z;
    const int tid = threadIdx.x;
    for (int e = tid; e < 4096; e += 256) {
        const int r = e >> 6, c = e & 63;  // r = d-local, c = l-local
        tile[r][c] = zb[(size_t)(b * 2048 + d0 + r) * 4096 + l0 + c];
    }
    __syncthreads();
    for (int e = tid; e < 4096; e += 256) {
        const int r = e >> 6, c = e & 63;  // r = l-local, c = d-local
        zt[(size_t)(b * 4096 + l0 + r) * 2048 + d0 + c] = (unsigned short)tile[c][r];
    }
}

// ---------- launch ----------
extern "C" void kernel_launch(void* const* d_in, const int* in_sizes, int n_in,
                              void* d_out, int out_size, void* d_ws, size_t ws_size,
                              hipStream_t stream)
{
    const float* x   = (const float*)d_in[0];
    const float* ipw = (const float*)d_in[1];
    const float* ipb = (const float*)d_in[2];
    const float* sw  = (const float*)d_in[3];
    const float* sb  = (const float*)d_in[4];
    const float* w0  = (const float*)d_in[5];
    const float* b0  = (const float*)d_in[6];
    const float* fr  = (const float*)d_in[7];
    const float* w1  = (const float*)d_in[8];
    const float* b1  = (const float*)d_in[9];
    const float* w2  = (const float*)d_in[10];
    const float* b2  = (const float*)d_in[11];
    const float* w3  = (const float*)d_in[12];
    const float* fb  = (const float*)d_in[13];
    const float* opw = (const float*)d_in[14];
    const float* opb = (const float*)d_in[15];
    float* out = (float*)d_out;

    // workspace layout (total exactly 256 MiB)
    char* ws = (char*)d_ws;
    unsigned short* xb  = (unsigned short*)ws;              // x  bf16   16,777,216
    unsigned short* wbi = xb + 16777216;                    // W_in bf16 12,582,912
    unsigned short* wbo = wbi + 12582912;                   // W_out bf16 4,194,304
    unsigned short* ub  = wbo + 4194304;                    // u (B,3D,L) bf16 50,331,648
    float* kf           = (float*)(ub + 50331648);          // k (D,L) f32 8,388,608
    unsigned short* zbm = (unsigned short*)(kf + 8388608);  // z (B,D,L) bf16 16,777,216
    unsigned short* ztb = zbm + 16777216;                   // z (B,L,D) bf16 16,777,216

    cvt_f32_bf16<<<1024, 256, 0, stream>>>(x,   xb,  16777216 / 4);
    cvt_f32_bf16<<<1024, 256, 0, stream>>>(ipw, wbi, 12582912 / 4);
    cvt_f32_bf16<<<512,  256, 0, stream>>>(opw, wbo, 4194304 / 4);

    // u = (x @ W_in^T + b) written transposed to (B, 3D, L)
    gemm_bf16<1><<<dim3(48, 64), 256, 0, stream>>>(xb, wbi, ipb, ub, 8192, 6144, 2048, 4096, 6144);

    filter_kernel<<<dim3(64, 8), 256, 0, stream>>>(w0, b0, fr, w1, b1, w2, b2, w3, kf);

    hyena_fft_kernel<<<2048, 512, 0, stream>>>(ub, kf, sw, sb, fb, zbm);

    transpose_kernel<<<dim3(64, 32, 2), 256, 0, stream>>>(zbm, ztb);

    // out = z @ W_out^T + b (f32)
    gemm_bf16<0><<<dim3(16, 64), 256, 0, stream>>>(ztb, wbo, opb, out, 8192, 2048, 2048, 4096, 2048);
}

// Round 3
// 991.403 us; speedup vs baseline: 1.0071x; 1.0071x over previous
//
#include <hip/hip_runtime.h>
#include <hip/hip_bf16.h>
#include <cstdint>
#include <cstddef>

// ---------- types ----------
typedef __attribute__((ext_vector_type(8))) short    bf16x8;   // 8 bf16 = 4 VGPRs (MFMA A/B frag)
typedef __attribute__((ext_vector_type(4))) float    f32x4;    // MFMA C/D frag
typedef __attribute__((ext_vector_type(8))) unsigned short u16x8;
typedef __attribute__((ext_vector_type(4))) float    f32v4;
typedef __attribute__((ext_vector_type(4))) unsigned short u16v4;

__device__ __forceinline__ float b2f(unsigned short v) {
    return __builtin_bit_cast(float, ((unsigned int)v) << 16);
}
__device__ __forceinline__ unsigned short f2b(float f) {
    unsigned int u = __builtin_bit_cast(unsigned int, f);
    u += 0x7fffu + ((u >> 16) & 1u);        // RNE
    return (unsigned short)(u >> 16);
}

__device__ __forceinline__ void async16(const void* g, void* l) {
    __builtin_amdgcn_global_load_lds(
        (const __attribute__((address_space(1))) unsigned int*)g,
        (__attribute__((address_space(3))) unsigned int*)l, 16, 0, 0);
}

// ---------- f32 -> bf16 convert ----------
__global__ __launch_bounds__(256) void cvt_f32_bf16(const float* __restrict__ src,
                                                    unsigned short* __restrict__ dst, int n4) {
    int i = blockIdx.x * blockDim.x + threadIdx.x;
    int stride = gridDim.x * blockDim.x;
    const f32v4* s4 = (const f32v4*)src;
    u16v4* d4 = (u16v4*)dst;
    for (; i < n4; i += stride) {
        f32v4 v = s4[i];
        u16v4 o;
        o.x = f2b(v.x); o.y = f2b(v.y); o.z = f2b(v.z); o.w = f2b(v.w);
        d4[i] = o;
    }
}

// ---------- bf16 MFMA GEMM: C[m][n] = sum_k A[m][k]*Bw[n][k] + bias[n] ----------
// MODE 0: Cout = float, row-major [M][N]
// MODE 1: Cout = bf16, "u layout": Cout[(b*CH + n)*Lseq + l], m = b*Lseq + l (tile never straddles b)
template <int MODE>
__global__ __launch_bounds__(256, 2) void gemm_bf16(
    const unsigned short* __restrict__ A,   // M x K bf16 row-major
    const unsigned short* __restrict__ Bw,  // N x K bf16 row-major
    const float* __restrict__ bias,         // N
    void* __restrict__ Cout,
    int M, int N, int K, int Lseq, int CH)
{
    constexpr int SMEM_N = (MODE == 1) ? 16384 : 8192;
    __shared__ unsigned short smem[SMEM_N];  // A tile [128][32] @0, B tile [128][32] @4096 (ushort idx)

    const int tid  = threadIdx.x;
    const int w    = tid >> 6;
    const int lane = tid & 63;
    const int quad = lane >> 4;
    const int lq   = lane & 15;
    const int n0 = blockIdx.x * 128;
    const int m0 = blockIdx.y * 128;
    const int wave_m = w & 1, wave_n = w >> 1;

    // staging: each wave copies 2KB of A + 2KB of B per K-step, 16B/lane/inst
    const int rSub = w * 32 + (lane >> 2);
    const int kcol = (lane & 3) * 8;
    const unsigned short* pA0 = A  + (size_t)(m0 + rSub)      * K + kcol;
    const unsigned short* pA1 = A  + (size_t)(m0 + rSub + 16) * K + kcol;
    const unsigned short* pB0 = Bw + (size_t)(n0 + rSub)      * K + kcol;
    const unsigned short* pB1 = Bw + (size_t)(n0 + rSub + 16) * K + kcol;
    char* sb = (char*)smem;
    char* dA0 = sb + w * 2048;
    char* dA1 = sb + w * 2048 + 1024;
    char* dB0 = sb + 8192 + w * 2048;
    char* dB1 = sb + 8192 + w * 2048 + 1024;

    f32x4 acc[4][4] = {};

    const int nIter = K >> 5;
    for (int kt = 0; kt < nIter; ++kt) {
        async16(pA0, dA0); async16(pA1, dA1);
        async16(pB0, dB0); async16(pB1, dB1);
        pA0 += 32; pA1 += 32; pB0 += 32; pB1 += 32;
        __syncthreads();   // drains vmcnt before LDS reads
        bf16x8 af[4], bw[4];
        #pragma unroll
        for (int i = 0; i < 4; ++i) {
            af[i] = *(const bf16x8*)&smem[(wave_m * 64 + i * 16 + lq) * 32 + quad * 8];
            bw[i] = *(const bf16x8*)&smem[4096 + (wave_n * 64 + i * 16 + lq) * 32 + quad * 8];
        }
        #pragma unroll
        for (int i = 0; i < 4; ++i)
            #pragma unroll
            for (int j = 0; j < 4; ++j)
                acc[i][j] = __builtin_amdgcn_mfma_f32_16x16x32_bf16(af[i], bw[j], acc[i][j], 0, 0, 0);
        __syncthreads();   // protect smem before next staging
    }

    if (MODE == 0) {
        float* out = (float*)Cout;
        #pragma unroll
        for (int j = 0; j < 4; ++j) {
            const int col = n0 + wave_n * 64 + j * 16 + lq;
            const float bv = bias[col];
            #pragma unroll
            for (int i = 0; i < 4; ++i) {
                const int rowb = m0 + wave_m * 64 + i * 16 + quad * 4;
                f32x4 c = acc[i][j];
                out[(size_t)(rowb + 0) * N + col] = c.x + bv;
                out[(size_t)(rowb + 1) * N + col] = c.y + bv;
                out[(size_t)(rowb + 2) * N + col] = c.z + bv;
                out[(size_t)(rowb + 3) * N + col] = c.w + bv;
            }
        }
    } else {
        // transpose through LDS so output rows (fixed channel, contiguous l) store coalesced
        #pragma unroll
        for (int j = 0; j < 4; ++j) {
            const int nl = wave_n * 64 + j * 16 + lq;
            const float bv = bias[n0 + nl];
            #pragma unroll
            for (int i = 0; i < 4; ++i) {
                const int ml = wave_m * 64 + i * 16 + quad * 4;
                f32x4 c = acc[i][j];
                smem[nl * 128 + ml + 0] = f2b(c.x + bv);
                smem[nl * 128 + ml + 1] = f2b(c.y + bv);
                smem[nl * 128 + ml + 2] = f2b(c.z + bv);
                smem[nl * 128 + ml + 3] = f2b(c.w + bv);
            }
        }
        __syncthreads();
        unsigned short* uo = (unsigned short*)Cout;
        const int bI = m0 >> 12;        // 4096 rows per batch
        const int l0 = m0 & 4095;
        // full 128x128 tile: 2048 chunks of 8 ushorts (16B/lane, coalesced)
        for (int e = tid; e < 2048; e += 256) {
            const int nl = e >> 4, seg = e & 15;
            u16x8 v = *(const u16x8*)&smem[nl * 128 + seg * 8];
            *(u16x8*)&uo[(size_t)(bI * CH + n0 + nl) * Lseq + l0 + seg * 8] = v;
        }
    }
}

// ---------- Hyena filter k(D,L) ----------
__global__ __launch_bounds__(256) void filter_kernel(
    const float* __restrict__ w0, const float* __restrict__ b0,
    const float* __restrict__ freq,
    const float* __restrict__ w1, const float* __restrict__ b1,
    const float* __restrict__ w2, const float* __restrict__ b2,
    const float* __restrict__ w3, float* __restrict__ kf)
{
    __shared__ float ha[64][64];
    __shared__ float hb[64][64];
    const int tid = threadIdx.x;
    const int l0 = blockIdx.x * 64;
    const int d0 = blockIdx.y * 256;
    const int l  = tid & 63;
    const int lg = l0 + l;
    const float tt = (float)lg * (1.0f / 4095.0f);
    const float wang = 6.283185307179586f * (float)lg * (1.0f / 4096.0f);
    const float a  = 1e-4f * wang;
    const float z0 = tt, z1 = cosf(a), z2 = -sinf(a);

    for (int e = tid; e < 4096; e += 256) {
        const int dim = e >> 6;
        float pre = z0 * w0[dim * 3] + z1 * w0[dim * 3 + 1] + z2 * w0[dim * 3 + 2] + b0[dim];
        ha[dim][l] = sinf(freq[dim] * pre);
    }
    __syncthreads();
    for (int e = tid; e < 4096; e += 256) {
        const int dim = e >> 6;
        float acc = b1[dim];
        #pragma unroll
        for (int jj = 0; jj < 64; ++jj) acc += w1[dim * 64 + jj] * ha[jj][l];
        hb[dim][l] = sinf(freq[dim] * acc);
    }
    __syncthreads();
    for (int e = tid; e < 4096; e += 256) {
        const int dim = e >> 6;
        float acc = b2[dim];
        #pragma unroll
        for (int jj = 0; jj < 64; ++jj) acc += w2[dim * 64 + jj] * hb[jj][l];
        ha[dim][l] = sinf(freq[dim] * acc);
    }
    __syncthreads();
    for (int d = d0 + (tid >> 6); d < d0 + 256; d += 4) {
        float acc = 0.f;
        #pragma unroll
        for (int jj = 0; jj < 64; ++jj) acc += w3[d * 64 + jj] * ha[jj][l];
        // deltas = linspace(ln(.01)/1.5, ln(.01)/0.3, 2048); decay = exp(-t*|delta|)
        const float delta = fabsf(-3.0701134573253944f + (-5.999245642062483e-3f) * (float)d);
        kf[(size_t)d * 4096 + lg] = acc * __expf(-tt * delta);
    }
}

// ================= register-resident 8192-pt FFT (512 thr, 16 pts/thr) =================
// Ownerships: A: p = t + 512 s | B: p = (t>>5)*512 + (t&31) + 32 s | C: p = 16 t + j
// DIF forward ends bit-reversed-contiguous (C); inverse DIT consumes C and ends at A.
// LDS padded idx + (idx>>5): all three access patterns are <=2-way (free) bank aliasing.
#define PIDX(i) ((i) + ((i) >> 5))

__device__ __forceinline__ void bfly_f(float& r1, float& i1, float& r2, float& i2, float wr, float wi) {
    float ur = r1, ui = i1, vr = r2, vi = i2;
    r1 = ur + vr; i1 = ui + vi;
    float dr = ur - vr, di = ui - vi;
    r2 = dr * wr - di * wi;
    i2 = dr * wi + di * wr;
}
__device__ __forceinline__ void bfly_i(float& r1, float& i1, float& r2, float& i2, float wr, float wi) {
    float vr = r2 * wr - i2 * wi, vi = r2 * wi + i2 * wr;
    float ur = r1, ui = i1;
    r1 = ur + vr; i1 = ui + vi;
    r2 = ur - vr; i2 = ui - vi;
}

// stage hm = STR*DS; j = tt + STR*(s mod DS); theta = -pi*j/hm (fwd) / +pi*j/hm (inv)
template <int DS, int STR>
__device__ __forceinline__ void fwd_stage(float* re, float* im, int tt) {
    float wr[8], wi[8];
    constexpr float c = -3.14159265358979f / (float)(STR * DS);
    #pragma unroll
    for (int k = 0; k < DS; ++k) __sincosf(c * (float)(tt + STR * k), &wi[k], &wr[k]);
    #pragma unroll
    for (int s = 0; s < 16; ++s)
        if ((s & DS) == 0)
            bfly_f(re[s], im[s], re[s + DS], im[s + DS], wr[s & (DS - 1)], wi[s & (DS - 1)]);
}
template <int DS, int STR>
__device__ __forceinline__ void inv_stage(float* re, float* im, int tt) {
    float wr[8], wi[8];
    constexpr float c = 3.14159265358979f / (float)(STR * DS);
    #pragma unroll
    for (int k = 0; k < DS; ++k) __sincosf(c * (float)(tt + STR * k), &wi[k], &wr[k]);
    #pragma unroll
    for (int s = 0; s < 16; ++s)
        if ((s & DS) == 0)
            bfly_i(re[s], im[s], re[s + DS], im[s + DS], wr[s & (DS - 1)], wi[s & (DS - 1)]);
}

__device__ __forceinline__ void xchg(float* re, float* im, float* fre, float* fim,
                                     int wbase, int wstr, int rbase, int rstr) {
    __syncthreads();           // protect prior reads of fre/fim
    #pragma unroll
    for (int s = 0; s < 16; ++s) {
        const int i = wbase + wstr * s;
        fre[PIDX(i)] = re[s]; fim[PIDX(i)] = im[s];
    }
    __syncthreads();
    #pragma unroll
    for (int s = 0; s < 16; ++s) {
        const int i = rbase + rstr * s;
        re[s] = fre[PIDX(i)]; im[s] = fim[PIDX(i)];
    }
}

__device__ void fwd_fft(float* re, float* im, float* fre, float* fim, int t) {
    const int off = t & 31, seg = t >> 5;
    fwd_stage<8, 512>(re, im, t);
    fwd_stage<4, 512>(re, im, t);
    fwd_stage<2, 512>(re, im, t);
    fwd_stage<1, 512>(re, im, t);
    xchg(re, im, fre, fim, t, 512, seg * 512 + off, 32);        // A -> B
    fwd_stage<8, 32>(re, im, off);
    fwd_stage<4, 32>(re, im, off);
    fwd_stage<2, 32>(re, im, off);
    fwd_stage<1, 32>(re, im, off);
    {   // hm = 16 (m = 32) across threads t ^ 16; j = off & 15 (thread-constant)
        float wr, wi;
        __sincosf(-3.14159265358979f * (float)(off & 15) / 16.0f, &wi, &wr);
        const bool hi = (off & 16) != 0;
        #pragma unroll
        for (int s = 0; s < 16; ++s) {
            float rr = __shfl_xor(re[s], 16);
            float ri = __shfl_xor(im[s], 16);
            if (!hi) { re[s] += rr; im[s] += ri; }
            else {
                float dr = rr - re[s], di = ri - im[s];
                re[s] = dr * wr - di * wi;
                im[s] = dr * wi + di * wr;
            }
        }
    }
    xchg(re, im, fre, fim, seg * 512 + off, 32, 16 * t, 1);     // B -> C
    fwd_stage<8, 1>(re, im, 0);
    fwd_stage<4, 1>(re, im, 0);
    fwd_stage<2, 1>(re, im, 0);
    fwd_stage<1, 1>(re, im, 0);
}

__device__ void inv_fft(float* re, float* im, float* fre, float* fim, int t) {
    const int off = t & 31, seg = t >> 5;
    inv_stage<1, 1>(re, im, 0);
    inv_stage<2, 1>(re, im, 0);
    inv_stage<4, 1>(re, im, 0);
    inv_stage<8, 1>(re, im, 0);
    xchg(re, im, fre, fim, 16 * t, 1, seg * 512 + off, 32);     // C -> B
    {   // hm = 16 (m = 32), conj twiddle; v' = W * x[p+16]
        float wr, wi;
        __sincosf(3.14159265358979f * (float)(off & 15) / 16.0f, &wi, &wr);
        const bool hi = (off & 16) != 0;
        #pragma unroll
        for (int s = 0; s < 16; ++s) {
            float rr = __shfl_xor(re[s], 16);
            float ri = __shfl_xor(im[s], 16);
            if (!hi) {           // u = own, v' = W * recv
                float vr = rr * wr - ri * wi, vi = rr * wi + ri * wr;
                re[s] += vr; im[s] += vi;
            } else {             // u = recv, v' = W * own
                float vr = re[s] * wr - im[s] * wi, vi = re[s] * wi + im[s] * wr;
                re[s] = rr - vr; im[s] = ri - vi;
            }
        }
    }
    inv_stage<1, 32>(re, im, off);
    inv_stage<2, 32>(re, im, off);
    inv_stage<4, 32>(re, im, off);
    inv_stage<8, 32>(re, im, off);
    xchg(re, im, fre, fim, seg * 512 + off, 32, t, 512);        // B -> A
    inv_stage<1, 512>(re, im, t);
    inv_stage<2, 512>(re, im, t);
    inv_stage<4, 512>(re, im, t);
    inv_stage<8, 512>(re, im, t);
}

// ---------- fused: short conv + gate + fftconv + bias + x0 gate -> zb (B,D,L) bf16 ----------
__global__ __launch_bounds__(512, 1) void hyena_fft_kernel(
    const unsigned short* __restrict__ u,   // (B, 3D, L) bf16
    const float* __restrict__ kf,           // (D, L)
    const float* __restrict__ sw,           // (3D, 1, 3)
    const float* __restrict__ sbv,          // (3D)
    const float* __restrict__ fbias,        // (D)
    unsigned short* __restrict__ zb)        // (B, D, L) bf16
{
    __shared__ float fre[8448];
    __shared__ float fim[8448];
    const int t = threadIdx.x;
    const int d = blockIdx.x;

    // ---- K = FFT(k_d zero-padded); ends in C ownership, stays in regs ----
    float kr[16], ki[16];
    #pragma unroll
    for (int s = 0; s < 16; ++s) {
        kr[s] = (s < 8) ? kf[(size_t)d * 4096 + t + 512 * s] : 0.f;
        ki[s] = 0.f;
    }
    fwd_fft(kr, ki, fre, fim, t);

    // ---- short conv (causal taps w0*u[l-2]+w1*u[l-1]+w2*u[l]) + gating, at A ownership ----
    const int c0 = d, c1 = 2048 + d, c2 = 4096 + d;
    const float w00 = sw[c0*3+0], w01 = sw[c0*3+1], w02 = sw[c0*3+2], bb0 = sbv[c0];
    const float w10 = sw[c1*3+0], w11 = sw[c1*3+1], w12 = sw[c1*3+2], bb1 = sbv[c1];
    const float w20 = sw[c2*3+0], w21 = sw[c2*3+1], w22 = sw[c2*3+2], bb2 = sbv[c2];
    const float fb = fbias[d];

    float vgr_[2][8], x0r_[2][8];
    float xr[16], xi[16];
    #pragma unroll
    for (int s = 0; s < 8; ++s) {
        const int l = t + (s << 9);
        #pragma unroll
        for (int b = 0; b < 2; ++b) {
            const size_t base = (size_t)b * 6144 * 4096;
            const size_t r0 = base + (size_t)c0 * 4096;
            const size_t r1 = base + (size_t)c1 * 4096;
            const size_t r2 = base + (size_t)c2 * 4096;
            const float a0 = b2f(u[r0 + l]);
            const float a1 = (l >= 1) ? b2f(u[r0 + l - 1]) : 0.f;
            const float a2 = (l >= 2) ? b2f(u[r0 + l - 2]) : 0.f;
            const float x0v = w00 * a2 + w01 * a1 + w02 * a0 + bb0;
            const float e0 = b2f(u[r1 + l]);
            const float e1 = (l >= 1) ? b2f(u[r1 + l - 1]) : 0.f;
            const float e2 = (l >= 2) ? b2f(u[r1 + l - 2]) : 0.f;
            const float x1v = w10 * e2 + w11 * e1 + w12 * e0 + bb1;
            const float g0 = b2f(u[r2 + l]);
            const float g1 = (l >= 1) ? b2f(u[r2 + l - 1]) : 0.f;
            const float g2 = (l >= 2) ? b2f(u[r2 + l - 2]) : 0.f;
            const float vv = w20 * g2 + w21 * g1 + w22 * g0 + bb2;
            const float vg = vv * x1v;
            vgr_[b][s] = vg; x0r_[b][s] = x0v;
            if (b == 0) xr[s] = vg; else xi[s] = vg;
        }
    }
    #pragma unroll
    for (int s = 8; s < 16; ++s) { xr[s] = 0.f; xi[s] = 0.f; }

    // ---- C = FFT(vg0 + i*vg1); pointwise *K in C ownership; inverse back to A ----
    fwd_fft(xr, xi, fre, fim, t);
    #pragma unroll
    for (int j = 0; j < 16; ++j) {
        const float cr = xr[j], ci = xi[j];
        xr[j] = cr * kr[j] - ci * ki[j];
        xi[j] = cr * ki[j] + ci * kr[j];
    }
    inv_fft(xr, xi, fre, fim, t);

    // ---- epilogue: y = IFFT/8192; z = (y + vg*fb) * x0 ----
    const float inv_n = 1.0f / 8192.0f;
    #pragma unroll
    for (int s = 0; s < 8; ++s) {
        const int p = t + (s << 9);
        const float z0 = (xr[s] * inv_n + vgr_[0][s] * fb) * x0r_[0][s];
        const float z1 = (xi[s] * inv_n + vgr_[1][s] * fb) * x0r_[1][s];
        zb[(size_t)d * 4096 + p]          = f2b(z0);
        zb[(size_t)(2048 + d) * 4096 + p] = f2b(z1);
    }
}

// ---------- (B,D,L) bf16 -> (B,L,D) bf16 transpose ----------
__global__ __launch_bounds__(256) void transpose_kernel(const unsigned short* __restrict__ zb,
                                                        unsigned short* __restrict__ zt)
{
    __shared__ unsigned int tile[64][65];
    const int l0 = blockIdx.x * 64, d0 = blockIdx.y * 64, b = blockIdx.z;
    const int tid = threadIdx.x;
    for (int e = tid; e < 4096; e += 256) {
        const int r = e >> 6, c = e & 63;  // r = d-local, c = l-local
        tile[r][c] = zb[(size_t)(b * 2048 + d0 + r) * 4096 + l0 + c];
    }
    __syncthreads();
    for (int e = tid; e < 4096; e += 256) {
        const int r = e >> 6, c = e & 63;  // r = l-local, c = d-local
        zt[(size_t)(b * 4096 + l0 + r) * 2048 + d0 + c] = (unsigned short)tile[c][r];
    }
}

// ---------- launch ----------
extern "C" void kernel_launch(void* const* d_in, const int* in_sizes, int n_in,
                              void* d_out, int out_size, void* d_ws, size_t ws_size,
                              hipStream_t stream)
{
    const float* x   = (const float*)d_in[0];
    const float* ipw = (const float*)d_in[1];
    const float* ipb = (const float*)d_in[2];
    const float* sw  = (const float*)d_in[3];
    const float* sb  = (const float*)d_in[4];
    const float* w0  = (const float*)d_in[5];
    const float* b0  = (const float*)d_in[6];
    const float* fr  = (const float*)d_in[7];
    const float* w1  = (const float*)d_in[8];
    const float* b1  = (const float*)d_in[9];
    const float* w2  = (const float*)d_in[10];
    const float* b2  = (const float*)d_in[11];
    const float* w3  = (const float*)d_in[12];
    const float* fb  = (const float*)d_in[13];
    const float* opw = (const float*)d_in[14];
    const float* opb = (const float*)d_in[15];
    float* out = (float*)d_out;

    // workspace layout (total exactly 256 MiB)
    char* ws = (char*)d_ws;
    unsigned short* xb  = (unsigned short*)ws;              // x  bf16   16,777,216
    unsigned short* wbi = xb + 16777216;                    // W_in bf16 12,582,912
    unsigned short* wbo = wbi + 12582912;                   // W_out bf16 4,194,304
    unsigned short* ub  = wbo + 4194304;                    // u (B,3D,L) bf16 50,331,648
    float* kf           = (float*)(ub + 50331648);          // k (D,L) f32 8,388,608
    unsigned short* zbm = (unsigned short*)(kf + 8388608);  // z (B,D,L) bf16 16,777,216
    unsigned short* ztb = zbm + 16777216;                   // z (B,L,D) bf16 16,777,216

    cvt_f32_bf16<<<1024, 256, 0, stream>>>(x,   xb,  16777216 / 4);
    cvt_f32_bf16<<<1024, 256, 0, stream>>>(ipw, wbi, 12582912 / 4);
    cvt_f32_bf16<<<512,  256, 0, stream>>>(opw, wbo, 4194304 / 4);

    // u = (x @ W_in^T + b) written transposed to (B, 3D, L)
    gemm_bf16<1><<<dim3(48, 64), 256, 0, stream>>>(xb, wbi, ipb, ub, 8192, 6144, 2048, 4096, 6144);

    filter_kernel<<<dim3(64, 8), 256, 0, stream>>>(w0, b0, fr, w1, b1, w2, b2, w3, kf);

    hyena_fft_kernel<<<2048, 512, 0, stream>>>(ub, kf, sw, sb, fb, zbm);

    transpose_kernel<<<dim3(64, 32, 2), 256, 0, stream>>>(zbm, ztb);

    // out = z @ W_out^T + b (f32)
    gemm_bf16<0><<<dim3(16, 64), 256, 0, stream>>>(ztb, wbo, opb, out, 8192, 2048, 2048, 4096, 2048);
}

// Round 4
// 887.362 us; speedup vs baseline: 1.1252x; 1.1172x over previous
//
#include <hip/hip_runtime.h>
#include <hip/hip_bf16.h>
#include <cstdint>
#include <cstddef>

// ---------- types ----------
typedef __attribute__((ext_vector_type(8))) short    bf16x8;   // 8 bf16 = 4 VGPRs (MFMA A/B frag)
typedef __attribute__((ext_vector_type(4))) float    f32x4;    // MFMA C/D frag
typedef __attribute__((ext_vector_type(8))) unsigned short u16x8;
typedef __attribute__((ext_vector_type(4))) float    f32v4;
typedef __attribute__((ext_vector_type(4))) unsigned short u16v4;

__device__ __forceinline__ float b2f(unsigned short v) {
    return __builtin_bit_cast(float, ((unsigned int)v) << 16);
}
__device__ __forceinline__ unsigned short f2b(float f) {
    unsigned int u = __builtin_bit_cast(unsigned int, f);
    u += 0x7fffu + ((u >> 16) & 1u);        // RNE
    return (unsigned short)(u >> 16);
}

__device__ __forceinline__ void async16(const void* g, void* l) {
    __builtin_amdgcn_global_load_lds(
        (const __attribute__((address_space(1))) unsigned int*)g,
        (__attribute__((address_space(3))) unsigned int*)l, 16, 0, 0);
}

// ---------- f32 -> bf16 convert ----------
__global__ __launch_bounds__(256) void cvt_f32_bf16(const float* __restrict__ src,
                                                    unsigned short* __restrict__ dst, int n4) {
    int i = blockIdx.x * blockDim.x + threadIdx.x;
    int stride = gridDim.x * blockDim.x;
    const f32v4* s4 = (const f32v4*)src;
    u16v4* d4 = (u16v4*)dst;
    for (; i < n4; i += stride) {
        f32v4 v = s4[i];
        u16v4 o;
        o.x = f2b(v.x); o.y = f2b(v.y); o.z = f2b(v.z); o.w = f2b(v.w);
        d4[i] = o;
    }
}

// ---------- bf16 MFMA GEMM: C[m][n] = sum_k A[m][k]*Bw[n][k] + bias[n] ----------
// MODE 0: Cout = float, row-major [M][N]
// MODE 1: Cout = bf16, "u layout": Cout[(b*CH + n)*Lseq + l], m = b*Lseq + l (tile never straddles b)
template <int MODE>
__global__ __launch_bounds__(256, 2) void gemm_bf16(
    const unsigned short* __restrict__ A,   // M x K bf16 row-major
    const unsigned short* __restrict__ Bw,  // N x K bf16 row-major
    const float* __restrict__ bias,         // N
    void* __restrict__ Cout,
    int M, int N, int K, int Lseq, int CH)
{
    constexpr int SMEM_N = (MODE == 1) ? 16384 : 8192;
    __shared__ unsigned short smem[SMEM_N];  // A tile [128][32] @0, B tile [128][32] @4096 (ushort idx)

    const int tid  = threadIdx.x;
    const int w    = tid >> 6;
    const int lane = tid & 63;
    const int quad = lane >> 4;
    const int lq   = lane & 15;
    const int n0 = blockIdx.x * 128;
    const int m0 = blockIdx.y * 128;
    const int wave_m = w & 1, wave_n = w >> 1;

    // staging: each wave copies 2KB of A + 2KB of B per K-step, 16B/lane/inst
    const int rSub = w * 32 + (lane >> 2);
    const int kcol = (lane & 3) * 8;
    const unsigned short* pA0 = A  + (size_t)(m0 + rSub)      * K + kcol;
    const unsigned short* pA1 = A  + (size_t)(m0 + rSub + 16) * K + kcol;
    const unsigned short* pB0 = Bw + (size_t)(n0 + rSub)      * K + kcol;
    const unsigned short* pB1 = Bw + (size_t)(n0 + rSub + 16) * K + kcol;
    char* sb = (char*)smem;
    char* dA0 = sb + w * 2048;
    char* dA1 = sb + w * 2048 + 1024;
    char* dB0 = sb + 8192 + w * 2048;
    char* dB1 = sb + 8192 + w * 2048 + 1024;

    f32x4 acc[4][4] = {};

    const int nIter = K >> 5;
    for (int kt = 0; kt < nIter; ++kt) {
        async16(pA0, dA0); async16(pA1, dA1);
        async16(pB0, dB0); async16(pB1, dB1);
        pA0 += 32; pA1 += 32; pB0 += 32; pB1 += 32;
        __syncthreads();   // drains vmcnt before LDS reads
        bf16x8 af[4], bw[4];
        #pragma unroll
        for (int i = 0; i < 4; ++i) {
            af[i] = *(const bf16x8*)&smem[(wave_m * 64 + i * 16 + lq) * 32 + quad * 8];
            bw[i] = *(const bf16x8*)&smem[4096 + (wave_n * 64 + i * 16 + lq) * 32 + quad * 8];
        }
        #pragma unroll
        for (int i = 0; i < 4; ++i)
            #pragma unroll
            for (int j = 0; j < 4; ++j)
                acc[i][j] = __builtin_amdgcn_mfma_f32_16x16x32_bf16(af[i], bw[j], acc[i][j], 0, 0, 0);
        __syncthreads();   // protect smem before next staging
    }

    if (MODE == 0) {
        float* out = (float*)Cout;
        #pragma unroll
        for (int j = 0; j < 4; ++j) {
            const int col = n0 + wave_n * 64 + j * 16 + lq;
            const float bv = bias[col];
            #pragma unroll
            for (int i = 0; i < 4; ++i) {
                const int rowb = m0 + wave_m * 64 + i * 16 + quad * 4;
                f32x4 c = acc[i][j];
                out[(size_t)(rowb + 0) * N + col] = c.x + bv;
                out[(size_t)(rowb + 1) * N + col] = c.y + bv;
                out[(size_t)(rowb + 2) * N + col] = c.z + bv;
                out[(size_t)(rowb + 3) * N + col] = c.w + bv;
            }
        }
    } else {
        // transpose through LDS so output rows (fixed channel, contiguous l) store coalesced
        #pragma unroll
        for (int j = 0; j < 4; ++j) {
            const int nl = wave_n * 64 + j * 16 + lq;
            const float bv = bias[n0 + nl];
            #pragma unroll
            for (int i = 0; i < 4; ++i) {
                const int ml = wave_m * 64 + i * 16 + quad * 4;
                f32x4 c = acc[i][j];
                smem[nl * 128 + ml + 0] = f2b(c.x + bv);
                smem[nl * 128 + ml + 1] = f2b(c.y + bv);
                smem[nl * 128 + ml + 2] = f2b(c.z + bv);
                smem[nl * 128 + ml + 3] = f2b(c.w + bv);
            }
        }
        __syncthreads();
        unsigned short* uo = (unsigned short*)Cout;
        const int bI = m0 >> 12;        // 4096 rows per batch
        const int l0 = m0 & 4095;
        // full 128x128 tile: 2048 chunks of 8 ushorts (16B/lane, coalesced)
        for (int e = tid; e < 2048; e += 256) {
            const int nl = e >> 4, seg = e & 15;
            u16x8 v = *(const u16x8*)&smem[nl * 128 + seg * 8];
            *(u16x8*)&uo[(size_t)(bI * CH + n0 + nl) * Lseq + l0 + seg * 8] = v;
        }
    }
}

// ---------- Hyena filter k(D,L) ----------
__global__ __launch_bounds__(256) void filter_kernel(
    const float* __restrict__ w0, const float* __restrict__ b0,
    const float* __restrict__ freq,
    const float* __restrict__ w1, const float* __restrict__ b1,
    const float* __restrict__ w2, const float* __restrict__ b2,
    const float* __restrict__ w3, float* __restrict__ kf)
{
    __shared__ float ha[64][64];
    __shared__ float hb[64][64];
    const int tid = threadIdx.x;
    const int l0 = blockIdx.x * 64;
    const int d0 = blockIdx.y * 256;
    const int l  = tid & 63;
    const int lg = l0 + l;
    const float tt = (float)lg * (1.0f / 4095.0f);
    const float wang = 6.283185307179586f * (float)lg * (1.0f / 4096.0f);
    const float a  = 1e-4f * wang;
    const float z0 = tt, z1 = cosf(a), z2 = -sinf(a);

    for (int e = tid; e < 4096; e += 256) {
        const int dim = e >> 6;
        float pre = z0 * w0[dim * 3] + z1 * w0[dim * 3 + 1] + z2 * w0[dim * 3 + 2] + b0[dim];
        ha[dim][l] = sinf(freq[dim] * pre);
    }
    __syncthreads();
    for (int e = tid; e < 4096; e += 256) {
        const int dim = e >> 6;
        float acc = b1[dim];
        #pragma unroll
        for (int jj = 0; jj < 64; ++jj) acc += w1[dim * 64 + jj] * ha[jj][l];
        hb[dim][l] = sinf(freq[dim] * acc);
    }
    __syncthreads();
    for (int e = tid; e < 4096; e += 256) {
        const int dim = e >> 6;
        float acc = b2[dim];
        #pragma unroll
        for (int jj = 0; jj < 64; ++jj) acc += w2[dim * 64 + jj] * hb[jj][l];
        ha[dim][l] = sinf(freq[dim] * acc);
    }
    __syncthreads();
    for (int d = d0 + (tid >> 6); d < d0 + 256; d += 4) {
        float acc = 0.f;
        #pragma unroll
        for (int jj = 0; jj < 64; ++jj) acc += w3[d * 64 + jj] * ha[jj][l];
        // deltas = linspace(ln(.01)/1.5, ln(.01)/0.3, 2048); decay = exp(-t*|delta|)
        const float delta = fabsf(-3.0701134573253944f + (-5.999245642062483e-3f) * (float)d);
        kf[(size_t)d * 4096 + lg] = acc * __expf(-tt * delta);
    }
}

// ================= register-resident 8192-pt FFT (512 thr, 16 pts/thr) =================
// Ownerships: A: p = t + 512 s | B: p = (t>>5)*512 + (t&31) + 32 s | C: p = 16 t + j
// DIF forward ends bit-reversed-contiguous (C); inverse DIT consumes C and ends at A.
// LDS padded idx + (idx>>5): all three access patterns are <=2-way (free) bank aliasing.
#define PIDX(i) ((i) + ((i) >> 5))

__device__ __forceinline__ void bfly_f(float& r1, float& i1, float& r2, float& i2, float wr, float wi) {
    float ur = r1, ui = i1, vr = r2, vi = i2;
    r1 = ur + vr; i1 = ui + vi;
    float dr = ur - vr, di = ui - vi;
    r2 = dr * wr - di * wi;
    i2 = dr * wi + di * wr;
}
__device__ __forceinline__ void bfly_i(float& r1, float& i1, float& r2, float& i2, float wr, float wi) {
    float vr = r2 * wr - i2 * wi, vi = r2 * wi + i2 * wr;
    float ur = r1, ui = i1;
    r1 = ur + vr; i1 = ui + vi;
    r2 = ur - vr; i2 = ui - vi;
}

// stage hm = STR*DS; j = tt + STR*(s mod DS); theta = -pi*j/hm (fwd) / +pi*j/hm (inv)
template <int DS, int STR>
__device__ __forceinline__ void fwd_stage(float* re, float* im, int tt) {
    float wr[8], wi[8];
    constexpr float c = -3.14159265358979f / (float)(STR * DS);
    #pragma unroll
    for (int k = 0; k < DS; ++k) __sincosf(c * (float)(tt + STR * k), &wi[k], &wr[k]);
    #pragma unroll
    for (int s = 0; s < 16; ++s)
        if ((s & DS) == 0)
            bfly_f(re[s], im[s], re[s + DS], im[s + DS], wr[s & (DS - 1)], wi[s & (DS - 1)]);
}
template <int DS, int STR>
__device__ __forceinline__ void inv_stage(float* re, float* im, int tt) {
    float wr[8], wi[8];
    constexpr float c = 3.14159265358979f / (float)(STR * DS);
    #pragma unroll
    for (int k = 0; k < DS; ++k) __sincosf(c * (float)(tt + STR * k), &wi[k], &wr[k]);
    #pragma unroll
    for (int s = 0; s < 16; ++s)
        if ((s & DS) == 0)
            bfly_i(re[s], im[s], re[s + DS], im[s + DS], wr[s & (DS - 1)], wi[s & (DS - 1)]);
}

__device__ __forceinline__ void xchg(float* re, float* im, float* fre, float* fim,
                                     int wbase, int wstr, int rbase, int rstr) {
    __syncthreads();           // protect prior reads of fre/fim
    #pragma unroll
    for (int s = 0; s < 16; ++s) {
        const int i = wbase + wstr * s;
        fre[PIDX(i)] = re[s]; fim[PIDX(i)] = im[s];
    }
    __syncthreads();
    #pragma unroll
    for (int s = 0; s < 16; ++s) {
        const int i = rbase + rstr * s;
        re[s] = fre[PIDX(i)]; im[s] = fim[PIDX(i)];
    }
}

__device__ __forceinline__ void fwd_fft(float* re, float* im, float* fre, float* fim, int t) {
    const int off = t & 31, seg = t >> 5;
    fwd_stage<8, 512>(re, im, t);
    fwd_stage<4, 512>(re, im, t);
    fwd_stage<2, 512>(re, im, t);
    fwd_stage<1, 512>(re, im, t);
    xchg(re, im, fre, fim, t, 512, seg * 512 + off, 32);        // A -> B
    fwd_stage<8, 32>(re, im, off);
    fwd_stage<4, 32>(re, im, off);
    fwd_stage<2, 32>(re, im, off);
    fwd_stage<1, 32>(re, im, off);
    {   // hm = 16 (m = 32) across threads t ^ 16; j = off & 15 (thread-constant)
        float wr, wi;
        __sincosf(-3.14159265358979f * (float)(off & 15) / 16.0f, &wi, &wr);
        const bool hi = (off & 16) != 0;
        #pragma unroll
        for (int s = 0; s < 16; ++s) {
            float rr = __shfl_xor(re[s], 16);
            float ri = __shfl_xor(im[s], 16);
            if (!hi) { re[s] += rr; im[s] += ri; }
            else {
                float dr = rr - re[s], di = ri - im[s];
                re[s] = dr * wr - di * wi;
                im[s] = dr * wi + di * wr;
            }
        }
    }
    xchg(re, im, fre, fim, seg * 512 + off, 32, 16 * t, 1);     // B -> C
    fwd_stage<8, 1>(re, im, 0);
    fwd_stage<4, 1>(re, im, 0);
    fwd_stage<2, 1>(re, im, 0);
    fwd_stage<1, 1>(re, im, 0);
}

__device__ __forceinline__ void inv_fft(float* re, float* im, float* fre, float* fim, int t) {
    const int off = t & 31, seg = t >> 5;
    inv_stage<1, 1>(re, im, 0);
    inv_stage<2, 1>(re, im, 0);
    inv_stage<4, 1>(re, im, 0);
    inv_stage<8, 1>(re, im, 0);
    xchg(re, im, fre, fim, 16 * t, 1, seg * 512 + off, 32);     // C -> B
    {   // hm = 16 (m = 32), conj twiddle; v' = W * x[p+16]
        float wr, wi;
        __sincosf(3.14159265358979f * (float)(off & 15) / 16.0f, &wi, &wr);
        const bool hi = (off & 16) != 0;
        #pragma unroll
        for (int s = 0; s < 16; ++s) {
            float rr = __shfl_xor(re[s], 16);
            float ri = __shfl_xor(im[s], 16);
            if (!hi) {           // u = own, v' = W * recv
                float vr = rr * wr - ri * wi, vi = rr * wi + ri * wr;
                re[s] += vr; im[s] += vi;
            } else {             // u = recv, v' = W * own
                float vr = re[s] * wr - im[s] * wi, vi = re[s] * wi + im[s] * wr;
                re[s] = rr - vr; im[s] = ri - vi;
            }
        }
    }
    inv_stage<1, 32>(re, im, off);
    inv_stage<2, 32>(re, im, off);
    inv_stage<4, 32>(re, im, off);
    inv_stage<8, 32>(re, im, off);
    xchg(re, im, fre, fim, seg * 512 + off, 32, t, 512);        // B -> A
    inv_stage<1, 512>(re, im, t);
    inv_stage<2, 512>(re, im, t);
    inv_stage<4, 512>(re, im, t);
    inv_stage<8, 512>(re, im, t);
}

// ---------- fused: short conv + gate + fftconv + bias + x0 gate -> zb (B,D,L) bf16 ----------
__global__ __launch_bounds__(512, 1) void hyena_fft_kernel(
    const unsigned short* __restrict__ u,   // (B, 3D, L) bf16
    const float* __restrict__ kf,           // (D, L)
    const float* __restrict__ sw,           // (3D, 1, 3)
    const float* __restrict__ sbv,          // (3D)
    const float* __restrict__ fbias,        // (D)
    unsigned short* __restrict__ zb)        // (B, D, L) bf16
{
    __shared__ float fre[8448];
    __shared__ float fim[8448];
    __shared__ float ksr[8192];   // K spectrum parked here, j-major [j*512 + t]
    __shared__ float ksi[8192];   // (stride-1 per wave -> conflict-free, const offsets)
    const int t = threadIdx.x;
    const int d = blockIdx.x;

    // ---- phase 1: K = FFT(k_d zero-padded), then park spectrum in LDS ----
    {
        float kr[16], ki[16];
        #pragma unroll
        for (int s = 0; s < 16; ++s) {
            kr[s] = (s < 8) ? kf[(size_t)d * 4096 + t + 512 * s] : 0.f;
            ki[s] = 0.f;
        }
        fwd_fft(kr, ki, fre, fim, t);
        #pragma unroll
        for (int j = 0; j < 16; ++j) { ksr[j * 512 + t] = kr[j]; ksi[j * 512 + t] = ki[j]; }
        // no barrier needed: each thread re-reads only its own kspec entries
    }

    // ---- phase 2: short conv (causal taps w0*u[l-2]+w1*u[l-1]+w2*u[l]) + gating, A ownership ----
    const int c0 = d, c1 = 2048 + d, c2 = 4096 + d;
    const float w00 = sw[c0*3+0], w01 = sw[c0*3+1], w02 = sw[c0*3+2], bb0 = sbv[c0];
    const float w10 = sw[c1*3+0], w11 = sw[c1*3+1], w12 = sw[c1*3+2], bb1 = sbv[c1];
    const float w20 = sw[c2*3+0], w21 = sw[c2*3+1], w22 = sw[c2*3+2], bb2 = sbv[c2];
    const float fb = fbias[d];

    float vgr_[2][8], x0r_[2][8];
    float xr[16], xi[16];
    #pragma unroll
    for (int s = 0; s < 8; ++s) {
        const int l = t + (s << 9);
        #pragma unroll
        for (int b = 0; b < 2; ++b) {
            const size_t base = (size_t)b * 6144 * 4096;
            const size_t r0 = base + (size_t)c0 * 4096;
            const size_t r1 = base + (size_t)c1 * 4096;
            const size_t r2 = base + (size_t)c2 * 4096;
            const float a0 = b2f(u[r0 + l]);
            const float a1 = (l >= 1) ? b2f(u[r0 + l - 1]) : 0.f;
            const float a2 = (l >= 2) ? b2f(u[r0 + l - 2]) : 0.f;
            const float x0v = w00 * a2 + w01 * a1 + w02 * a0 + bb0;
            const float e0 = b2f(u[r1 + l]);
            const float e1 = (l >= 1) ? b2f(u[r1 + l - 1]) : 0.f;
            const float e2 = (l >= 2) ? b2f(u[r1 + l - 2]) : 0.f;
            const float x1v = w10 * e2 + w11 * e1 + w12 * e0 + bb1;
            const float g0 = b2f(u[r2 + l]);
            const float g1 = (l >= 1) ? b2f(u[r2 + l - 1]) : 0.f;
            const float g2 = (l >= 2) ? b2f(u[r2 + l - 2]) : 0.f;
            const float vv = w20 * g2 + w21 * g1 + w22 * g0 + bb2;
            const float vg = vv * x1v;
            vgr_[b][s] = vg; x0r_[b][s] = x0v;
            if (b == 0) xr[s] = vg; else xi[s] = vg;
        }
    }
    #pragma unroll
    for (int s = 8; s < 16; ++s) { xr[s] = 0.f; xi[s] = 0.f; }

    // ---- phase 3: C = FFT(vg0 + i*vg1); pointwise *K (from LDS) in C ownership; inverse to A ----
    fwd_fft(xr, xi, fre, fim, t);
    #pragma unroll
    for (int j = 0; j < 16; ++j) {
        const float krj = ksr[j * 512 + t], kij = ksi[j * 512 + t];
        const float cr = xr[j], ci = xi[j];
        xr[j] = cr * krj - ci * kij;
        xi[j] = cr * kij + ci * krj;
    }
    inv_fft(xr, xi, fre, fim, t);

    // ---- epilogue: y = IFFT/8192; z = (y + vg*fb) * x0 ----
    const float inv_n = 1.0f / 8192.0f;
    #pragma unroll
    for (int s = 0; s < 8; ++s) {
        const int p = t + (s << 9);
        const float z0 = (xr[s] * inv_n + vgr_[0][s] * fb) * x0r_[0][s];
        const float z1 = (xi[s] * inv_n + vgr_[1][s] * fb) * x0r_[1][s];
        zb[(size_t)d * 4096 + p]          = f2b(z0);
        zb[(size_t)(2048 + d) * 4096 + p] = f2b(z1);
    }
}

// ---------- (B,D,L) bf16 -> (B,L,D) bf16 transpose ----------
__global__ __launch_bounds__(256) void transpose_kernel(const unsigned short* __restrict__ zb,
                                                        unsigned short* __restrict__ zt)
{
    __shared__ unsigned int tile[64][65];
    const int l0 = blockIdx.x * 64, d0 = blockIdx.y * 64, b = blockIdx.z;
    const int tid = threadIdx.x;
    for (int e = tid; e < 4096; e += 256) {
        const int r = e >> 6, c = e & 63;  // r = d-local, c = l-local
        tile[r][c] = zb[(size_t)(b * 2048 + d0 + r) * 4096 + l0 + c];
    }
    __syncthreads();
    for (int e = tid; e < 4096; e += 256) {
        const int r = e >> 6, c = e & 63;  // r = l-local, c = d-local
        zt[(size_t)(b * 4096 + l0 + r) * 2048 + d0 + c] = (unsigned short)tile[c][r];
    }
}

// ---------- launch ----------
extern "C" void kernel_launch(void* const* d_in, const int* in_sizes, int n_in,
                              void* d_out, int out_size, void* d_ws, size_t ws_size,
                              hipStream_t stream)
{
    const float* x   = (const float*)d_in[0];
    const float* ipw = (const float*)d_in[1];
    const float* ipb = (const float*)d_in[2];
    const float* sw  = (const float*)d_in[3];
    const float* sb  = (const float*)d_in[4];
    const float* w0  = (const float*)d_in[5];
    const float* b0  = (const float*)d_in[6];
    const float* fr  = (const float*)d_in[7];
    const float* w1  = (const float*)d_in[8];
    const float* b1  = (const float*)d_in[9];
    const float* w2  = (const float*)d_in[10];
    const float* b2  = (const float*)d_in[11];
    const float* w3  = (const float*)d_in[12];
    const float* fb  = (const float*)d_in[13];
    const float* opw = (const float*)d_in[14];
    const float* opb = (const float*)d_in[15];
    float* out = (float*)d_out;

    // workspace layout (total exactly 256 MiB)
    char* ws = (char*)d_ws;
    unsigned short* xb  = (unsigned short*)ws;              // x  bf16   16,777,216
    unsigned short* wbi = xb + 16777216;                    // W_in bf16 12,582,912
    unsigned short* wbo = wbi + 12582912;                   // W_out bf16 4,194,304
    unsigned short* ub  = wbo + 4194304;                    // u (B,3D,L) bf16 50,331,648
    float* kf           = (float*)(ub + 50331648);          // k (D,L) f32 8,388,608
    unsigned short* zbm = (unsigned short*)(kf + 8388608);  // z (B,D,L) bf16 16,777,216
    unsigned short* ztb = zbm + 16777216;                   // z (B,L,D) bf16 16,777,216

    cvt_f32_bf16<<<1024, 256, 0, stream>>>(x,   xb,  16777216 / 4);
    cvt_f32_bf16<<<1024, 256, 0, stream>>>(ipw, wbi, 12582912 / 4);
    cvt_f32_bf16<<<512,  256, 0, stream>>>(opw, wbo, 4194304 / 4);

    // u = (x @ W_in^T + b) written transposed to (B, 3D, L)
    gemm_bf16<1><<<dim3(48, 64), 256, 0, stream>>>(xb, wbi, ipb, ub, 8192, 6144, 2048, 4096, 6144);

    filter_kernel<<<dim3(64, 8), 256, 0, stream>>>(w0, b0, fr, w1, b1, w2, b2, w3, kf);

    hyena_fft_kernel<<<2048, 512, 0, stream>>>(ub, kf, sw, sb, fb, zbm);

    transpose_kernel<<<dim3(64, 32, 2), 256, 0, stream>>>(zbm, ztb);

    // out = z @ W_out^T + b (f32)
    gemm_bf16<0><<<dim3(16, 64), 256, 0, stream>>>(ztb, wbo, opb, out, 8192, 2048, 2048, 4096, 2048);
}